// Round 21
// baseline (46.404 us; speedup 1.0000x reference)
//
#include <hip/hip_runtime.h>
#include <math.h>

// ConcentrationPredictor: 32 RK4 steps of dc/dt = flux(c), per-cell MLP D_eff.
// R21 = R20 (single rk4 dispatch, TPB=512, inner 256, grid 256 = 1 block/CU,
// asinh-space cubic-Hermite table in duplicated-pair float4 layout -> one
// ds_read_b128 per eval, per-stage barriers, hoisted gathers, LDS A[s],
// sentinel halo buffers, fast-math build_tab) + RAW BARRIER in the stage
// loop: __syncthreads emits `s_waitcnt vmcnt(0) lgkmcnt(0)` before s_barrier,
// so each of the 128 stage barriers waited for that stage's OUTPUT STORE to
// retire (~100-200cyc of HBM/L2 store latency on the convoy path, per stage).
// The loop's only cross-thread dependency is LDS -> replace with
// `s_waitcnt lgkmcnt(0); s_barrier` (memory clobber + sched_barrier fences
// per guide rule #18). Output stores drain in the background.
// No arithmetic change -> absmax must stay exactly 131072 (race detector).

constexpr int TPB     = 512;
constexpr int S_FUSE  = 32;
constexpr int HALO    = 4 * S_FUSE;        // 128
constexpr int B_INNER = TPB - 2 * HALO;    // 256

constexpr int   NTAB   = 5633;             // nodes: u in [-22,22], h = 1/128
constexpr float VSLOPE = 88.72283911167299f;  // ln2 * 128
constexpr float VOFF   = 2816.0f;             // -U_MIN * 128
constexpr float HSTEP  = 0.0078125f;          // h = 1/128
constexpr int   NSEG   = NTAB - 1;            // 5632 float4 segments

// float-layout of d_ws / LDS:
//   [0 .. 4*NSEG)        float4 tab4[i] = (v_i, d_i, v_{i+1}, d_{i+1})
//   [4*NSEG]             scale = 10^p_exp
//   [4*NSEG+1 .. +32]    A[s] = (t[s+1]-t[s]) * 0.3125f
constexpr int F_SCALE = 4 * NSEG;          // 22528
constexpr int F_A0    = 4 * NSEG + 1;      // 22529
constexpr int F_TOT   = 4 * NSEG + 1 + 32; // 22561
constexpr int F4_TOT  = (F_TOT + 3) / 4;   // 5641 float4s staged

__device__ __forceinline__ float fast_tanh(float x) {
    float e = __expf(2.0f * x);
    return 1.0f - 2.0f * __builtin_amdgcn_rcpf(1.0f + e);
}

// ---------- prep: build ret table (value + d/du), duplicated-pair layout ----
__global__ __launch_bounds__(256)
void build_tab_kernel(const float* __restrict__ W1, const float* __restrict__ b1,
                      const float* __restrict__ W2, const float* __restrict__ b2,
                      const float* __restrict__ W3, const float* __restrict__ b3,
                      const float* __restrict__ W4, const float* __restrict__ b4,
                      const float* __restrict__ p_exp, const float* __restrict__ t,
                      int nsteps, float* __restrict__ wsf)
{
    const int i = blockIdx.x * blockDim.x + threadIdx.x;
    if (i > NTAB) {
        const int s = i - NTAB - 1;          // aux: A[s]
        if (s < nsteps && s < 32)
            wsf[F_A0 + s] = (t[s + 1] - t[s]) * 0.3125f;
        return;
    }
    if (i == NTAB) {                          // aux: scale
        wsf[F_SCALE] = powf(10.0f, p_exp[0]);
        return;
    }
    const float u  = -22.0f + (float)i * HSTEP;
    const float y  = sinhf(u);     // MLP input at this node
    const float yd = coshf(u);     // dy/du

    float h[15], hd[15], g[15], gd[15];
#pragma unroll
    for (int j = 0; j < 15; ++j) {
        float a  = fmaf(y, W1[j], b1[j]);
        float ad = yd * W1[j];
        float th = fast_tanh(a);
        h[j]  = th;
        hd[j] = (1.0f - th * th) * ad;
    }
#pragma unroll
    for (int j = 0; j < 15; ++j) {
        float a = b2[j], ad = 0.0f;
#pragma unroll
        for (int k = 0; k < 15; ++k) {
            a  = fmaf(h[k],  W2[k * 15 + j], a);
            ad = fmaf(hd[k], W2[k * 15 + j], ad);
        }
        float th = fast_tanh(a);
        g[j]  = th;
        gd[j] = (1.0f - th * th) * ad;
    }
#pragma unroll
    for (int j = 0; j < 15; ++j) {
        float a = b3[j], ad = 0.0f;
#pragma unroll
        for (int k = 0; k < 15; ++k) {
            a  = fmaf(g[k],  W3[k * 15 + j], a);
            ad = fmaf(gd[k], W3[k * 15 + j], ad);
        }
        float th = fast_tanh(a);
        h[j]  = th;
        hd[j] = (1.0f - th * th) * ad;
    }
    float o = b4[0], od = 0.0f;
#pragma unroll
    for (int k = 0; k < 15; ++k) {
        o  = fmaf(h[k],  W4[k], o);
        od = fmaf(hd[k], W4[k], od);
    }
    const float s = __builtin_amdgcn_rcpf(1.0f + __expf(-o));   // sigmoid
    const float d = s * (1.0f - s) * od;
    // duplicated-pair layout: node i is the left end of segment i and the
    // right end of segment i-1
    if (i < NSEG) {
        wsf[4 * i]     = s;       // tab4[i].x = v_i
        wsf[4 * i + 1] = d;       // tab4[i].y = d_i
    }
    if (i > 0) {
        wsf[4 * (i - 1) + 2] = s; // tab4[i-1].z = v_i
        wsf[4 * (i - 1) + 3] = d; // tab4[i-1].w = d_i
    }
}

// ---------- table evaluation: one ds_read_b128 + cubic Hermite --------------
__device__ __forceinline__ float ret_tab(float c, float scale,
                                         const float4* __restrict__ tab4)
{
    const float y  = c * scale;
    const float ay = fabsf(y);
    // u = asinh(y); v = (u + 22)*128 folded into one fma off v_log_f32 (log2)
    const float w  = ay + __builtin_amdgcn_sqrtf(fmaf(ay, ay, 1.0f));
    const float m  = copysignf(VSLOPE, y);
    float v = fmaf(__builtin_amdgcn_logf(w), m, VOFF);
    v = fminf(fmaxf(v, 0.0f), (float)(NSEG - 1) + 0.999f);  // clamp to table
    const int   i   = (int)v;
    const float tau = v - (float)i;

    const float4 AB = tab4[i];       // (v_i, d_i, v_{i+1}, d_{i+1})
    const float t2 = tau * tau;
    const float t3 = t2 * tau;
    return AB.x * (2.0f * t3 - 3.0f * t2 + 1.0f)
         + AB.z * (3.0f * t2 - 2.0f * t3)
         + HSTEP * (AB.y * (t3 - 2.0f * t2 + tau) + AB.w * (t3 - t2));
}

// flux/D0 (D0 folded into the A coefficient)
__device__ __forceinline__ float flux_cell(float ret, float c, float cl, float cr,
                                           int g, int N)
{
    if (g == 0)
        return ret * ((1.0f - c) + (cr - c));
    if (g == N - 1) {
        float rbc = 0.0125f * (cl - c);   // D0*DX*(c[N-2]-c[N-1])
        return ret * ((cl - c) + (rbc - c));
    }
    return ret * (cl + cr - 2.0f * c);
}

// LDS-only barrier: drain lgkmcnt (LDS writes/reads) but NOT vmcnt, so the
// per-stage output stores retire in the background instead of stalling the
// convoy. Memory clobber orders surrounding LDS ops; sched_barrier(0) stops
// the machine scheduler hoisting post-barrier ds_reads (guide rule #18).
#define STAGE_BARRIER()                                            \
    do {                                                           \
        __builtin_amdgcn_sched_barrier(0);                         \
        asm volatile("s_waitcnt lgkmcnt(0)\n\ts_barrier" ::: "memory"); \
        __builtin_amdgcn_sched_barrier(0);                         \
    } while (0)

__global__ __launch_bounds__(TPB)
void rk4_steps_kernel(const float* __restrict__ src,   // state at step s0 [N]
                      float* __restrict__ out,         // [T, N]
                      const float* __restrict__ wsf,   // table+aux in d_ws
                      int N, int s0, int nsub)
{
    __shared__ float tlds[F4_TOT * 4];   // table + aux (float4-staged, ~90KB)
    __shared__ float la[TPB + 2];        // sentinel slots [0] and [TPB+1]
    __shared__ float lb[TPB + 2];

    const int tid = threadIdx.x;

    // stage table+aux, float4-vectorized
    {
        const float4* __restrict__ s4 = (const float4*)wsf;
        float4* d4 = (float4*)tlds;
        for (int i = tid; i < F4_TOT; i += TPB) d4[i] = s4[i];
    }

    const int g  = blockIdx.x * B_INNER - HALO + tid;  // my global cell (may be OOB)
    const int gi = min(max(g, 0), N - 1);              // clamped load index

    float c = src[gi];

    const bool valid = (tid >= HALO) && (tid < HALO + B_INNER) && (g < N);

    // single launch also writes row 0 (replaces the D2D memcpy)
    if (s0 == 0 && valid) out[g] = c;

    __syncthreads();                  // table staged (full barrier, one-time)
    const float4* __restrict__ tab4 = (const float4*)tlds;
    const float scale = tlds[F_SCALE];

    for (int s = 0; s < nsub; ++s) {
        const float A = tlds[F_A0 + s];   // uniform broadcast, dt*D0

        // stage 1: gather hoisted above write+barrier (latency folds into
        // the barrier's lgkmcnt wait)
        float ret1 = ret_tab(c, scale, tab4);
        la[tid + 1] = c;
        STAGE_BARRIER();
        float cl = la[tid], cr = la[tid + 2];
        float k1 = flux_cell(ret1, c, cl, cr, g, N);
        float c2 = fmaf(0.5f * A, k1, c);

        // stage 2
        float ret2 = ret_tab(c2, scale, tab4);
        lb[tid + 1] = c2;
        STAGE_BARRIER();
        cl = lb[tid]; cr = lb[tid + 2];
        float k2 = flux_cell(ret2, c2, cl, cr, g, N);
        float c3 = fmaf(0.5f * A, k2, c);

        // stage 3
        float ret3 = ret_tab(c3, scale, tab4);
        la[tid + 1] = c3;
        STAGE_BARRIER();
        cl = la[tid]; cr = la[tid + 2];
        float k3 = flux_cell(ret3, c3, cl, cr, g, N);
        float c4 = fmaf(A, k3, c);

        // stage 4
        float ret4 = ret_tab(c4, scale, tab4);
        lb[tid + 1] = c4;
        STAGE_BARRIER();
        cl = lb[tid]; cr = lb[tid + 2];
        float k4 = flux_cell(ret4, c4, cl, cr, g, N);

        c = fmaf(A * (1.0f / 6.0f), k1 + 2.0f * (k2 + k3) + k4, c);

        // write valid inner window of this step's new state (store retires
        // in the background; no barrier ever waits on vmcnt)
        if (valid)
            out[(size_t)(s0 + s + 1) * N + g] = c;
    }
}

extern "C" void kernel_launch(void* const* d_in, const int* in_sizes, int n_in,
                              void* d_out, int out_size, void* d_ws, size_t ws_size,
                              hipStream_t stream)
{
    const float* c0    = (const float*)d_in[0];
    const float* t     = (const float*)d_in[1];
    const float* W1    = (const float*)d_in[2];
    const float* b1    = (const float*)d_in[3];
    const float* W2    = (const float*)d_in[4];
    const float* b2    = (const float*)d_in[5];
    const float* W3    = (const float*)d_in[6];
    const float* b3    = (const float*)d_in[7];
    const float* W4    = (const float*)d_in[8];
    const float* b4    = (const float*)d_in[9];
    const float* p_exp = (const float*)d_in[10];

    float* out = (float*)d_out;
    float* wsf = (float*)d_ws;   // F_TOT floats = 90244 B

    const int N      = in_sizes[0];       // 65536
    const int nsteps = in_sizes[1] - 1;   // 32

    // build ret table + aux (scale, A[s])
    const int tgrid = (NTAB + 1 + 32 + 255) / 256;
    hipLaunchKernelGGL(build_tab_kernel, dim3(tgrid), dim3(256), 0, stream,
                       W1, b1, W2, b2, W3, b3, W4, b4, p_exp, t, nsteps, wsf);

    const int grid = (N + B_INNER - 1) / B_INNER;  // 256 -> 1 block/CU

    for (int s0 = 0; s0 < nsteps; s0 += S_FUSE) {   // single iteration for T=33
        const int nsub = min(S_FUSE, nsteps - s0);
        const float* src = (s0 == 0) ? c0 : out + (size_t)s0 * N;
        hipLaunchKernelGGL(rk4_steps_kernel, dim3(grid), dim3(TPB), 0, stream,
                           src, out, wsf, N, s0, nsub);
    }
}